// Round 6
// baseline (112.162 us; speedup 1.0000x reference)
//
#include <hip/hip_runtime.h>
#include <hip/hip_bf16.h>
#include <cstdint>
#include <cstddef>

#define NS 2560
#define NQ 8192
#define NC 512
#define DD 1600

typedef __bf16 bf16_t;
typedef __bf16 bf16x8 __attribute__((ext_vector_type(8)));
typedef float f32x4 __attribute__((ext_vector_type(4)));

// ---------------------------------------------------------------------------
// Kernel 1: class-mean prototypes (bf16) + ||p||^2 (fp32). One block per class.
// ---------------------------------------------------------------------------
__global__ __launch_bounds__(256) void proto_kernel(
    const float* __restrict__ sup, const int* __restrict__ lab,
    bf16_t* __restrict__ protos, float* __restrict__ p2)
{
    const int m   = blockIdx.x;
    const int tid = threadIdx.x;
    __shared__ int   idxs[32];
    __shared__ int   cnt;
    __shared__ float wsum[4];
    if (tid == 0) cnt = 0;
    __syncthreads();
    for (int i = tid; i < NS; i += 256) {
        if (lab[i] == m) {
            int p = atomicAdd(&cnt, 1);
            if (p < 32) idxs[p] = i;
        }
    }
    __syncthreads();
    int n = cnt < 32 ? cnt : 32;
    if (tid == 0 && n > 1) {                       // deterministic order
        for (int a = 1; a < n; ++a) {
            int key = idxs[a]; int b = a - 1;
            while (b >= 0 && idxs[b] > key) { idxs[b+1] = idxs[b]; --b; }
            idxs[b+1] = key;
        }
    }
    __syncthreads();

    float acc[7];
    #pragma unroll
    for (int u = 0; u < 7; ++u) acc[u] = 0.f;
    for (int t = 0; t < n; ++t) {
        const float* src = sup + (size_t)idxs[t] * DD;
        #pragma unroll
        for (int u = 0; u < 7; ++u) {
            int j = tid + u * 256;
            if (j < DD) acc[u] += src[j];
        }
    }
    float inv = (n > 0) ? 1.f / (float)n : 0.f;
    float psq = 0.f;
    #pragma unroll
    for (int u = 0; u < 7; ++u) {
        int j = tid + u * 256;
        if (j < DD) {
            float p = acc[u] * inv;
            bf16_t pb = (bf16_t)p;
            protos[(size_t)m * DD + j] = pb;
            float pf = (float)pb;
            psq += pf * pf;
        }
    }
    #pragma unroll
    for (int o = 32; o > 0; o >>= 1) psq += __shfl_xor(psq, o);
    int lane = tid & 63, wid = tid >> 6;
    if (lane == 0) wsum[wid] = psq;
    __syncthreads();
    if (tid == 0) p2[m] = wsum[0] + wsum[1] + wsum[2] + wsum[3];
}

// ---------------------------------------------------------------------------
// Kernel 2 (fused, ALL-REGISTER main loop, ZERO barriers until epilogue):
// 32 query rows x ALL 512 classes per block; wave w owns cols [w*64,w*64+64).
// K=1600 in 25 steps of BK=64, 16 MFMA (16x16x32) per step.
//   A-frag(lane r,g; mi,kk) = q[m0+mi*16+r][T*64+kk*32+g*8 ..+8]: two float4
//     direct global loads + in-reg fp32->bf16 cvt. All 8 waves read the same
//     8 KB/iter -> L1-served after first wave.
//   B-frag(ni,kk) = 16 contiguous bytes of protos[wid*64+ni*16+r]: one
//     global_load_dwordx4. Protos (1.6 MB) is L2-resident per XCD.
// Both pipelined 1 tile ahead in rotating NAMED register sets (rule #20).
// No LDS, no s_barrier in the loop -> waves free-run, loads hoist freely.
// Epilogue: logits = 2*dot - |p|^2, cross-wave log_softmax via tiny LDS.
// ---------------------------------------------------------------------------
__device__ __forceinline__ void gemm_body(
    bf16x8 (&BC)[8], bf16x8 (&BN)[8], bf16x8 (&AC)[4], bf16x8 (&AN)[4],
    int T, const char* bbase, const float* abase, f32x4 (&acc)[2][4])
{
    const int  Tn  = T + 1;
    const bool pre = (Tn < 25);

    // ---- issue next tile's loads: A fp32 first, then B ----
    float4 fA[8];
    if (pre) {
        #pragma unroll
        for (int mi = 0; mi < 2; ++mi)
            #pragma unroll
            for (int kk = 0; kk < 2; ++kk)
                #pragma unroll
                for (int h = 0; h < 2; ++h)
                    fA[(mi * 2 + kk) * 2 + h] = *(const float4*)(abase
                        + (size_t)mi * 16 * DD + Tn * 64 + kk * 32 + h * 4);
        #pragma unroll
        for (int ni = 0; ni < 4; ++ni)
            #pragma unroll
            for (int kk = 0; kk < 2; ++kk)
                BN[ni * 2 + kk] = *(const bf16x8*)(bbase
                    + (size_t)ni * (16 * 2 * DD) + Tn * 128 + kk * 64);
    }

    // ---- 16 MFMA on current tile (all operands already in regs) ----
    #pragma unroll
    for (int kk = 0; kk < 2; ++kk)
        #pragma unroll
        for (int mi = 0; mi < 2; ++mi)
            #pragma unroll
            for (int ni = 0; ni < 4; ++ni)
                acc[mi][ni] = __builtin_amdgcn_mfma_f32_16x16x32_bf16(
                    AC[kk * 2 + mi], BC[ni * 2 + kk], acc[mi][ni], 0, 0, 0);

    // ---- convert A(t+1) fp32 -> bf16 (waits only on the A loads) ----
    if (pre) {
        #pragma unroll
        for (int mi = 0; mi < 2; ++mi)
            #pragma unroll
            for (int kk = 0; kk < 2; ++kk) {
                float4 lo = fA[(mi * 2 + kk) * 2];
                float4 hi = fA[(mi * 2 + kk) * 2 + 1];
                bf16x8 w;
                w[0] = (bf16_t)lo.x; w[1] = (bf16_t)lo.y;
                w[2] = (bf16_t)lo.z; w[3] = (bf16_t)lo.w;
                w[4] = (bf16_t)hi.x; w[5] = (bf16_t)hi.y;
                w[6] = (bf16_t)hi.z; w[7] = (bf16_t)hi.w;
                AN[kk * 2 + mi] = w;
            }
    }
}

__global__ __launch_bounds__(512, 2) void fused_kernel(
    const float* __restrict__ q, const bf16_t* __restrict__ protos,
    const float* __restrict__ p2, float* __restrict__ out)
{
    __shared__ float red[32 * 8];
    __shared__ float gmaxs[32];
    __shared__ float lses[32];

    const int tid  = threadIdx.x;
    const int lane = tid & 63;
    const int wid  = tid >> 6;        // wave = 64-col strip 0..7
    const int r    = lane & 15;
    const int g    = lane >> 4;
    const int m0   = blockIdx.x * 32;

    // per-lane bases
    const char*  bbase = (const char*)protos
                       + (size_t)(wid * 64 + r) * (2 * DD) + g * 16;
    const float* abase = q + (size_t)(m0 + r) * DD + g * 8;

    float p2c[4];
    #pragma unroll
    for (int ni = 0; ni < 4; ++ni) p2c[ni] = p2[wid * 64 + ni * 16 + r];

    f32x4 acc[2][4];
    #pragma unroll
    for (int mi = 0; mi < 2; ++mi)
        #pragma unroll
        for (int ni = 0; ni < 4; ++ni)
            acc[mi][ni] = (f32x4){0.f, 0.f, 0.f, 0.f};

    bf16x8 a0[4], a1[4], b0[8], b1[8];

    // ---- prologue: load + convert tile 0 ----
    {
        float4 fA[8];
        #pragma unroll
        for (int mi = 0; mi < 2; ++mi)
            #pragma unroll
            for (int kk = 0; kk < 2; ++kk)
                #pragma unroll
                for (int h = 0; h < 2; ++h)
                    fA[(mi * 2 + kk) * 2 + h] = *(const float4*)(abase
                        + (size_t)mi * 16 * DD + kk * 32 + h * 4);
        #pragma unroll
        for (int ni = 0; ni < 4; ++ni)
            #pragma unroll
            for (int kk = 0; kk < 2; ++kk)
                b0[ni * 2 + kk] = *(const bf16x8*)(bbase
                    + (size_t)ni * (16 * 2 * DD) + kk * 64);
        #pragma unroll
        for (int mi = 0; mi < 2; ++mi)
            #pragma unroll
            for (int kk = 0; kk < 2; ++kk) {
                float4 lo = fA[(mi * 2 + kk) * 2];
                float4 hi = fA[(mi * 2 + kk) * 2 + 1];
                bf16x8 w;
                w[0] = (bf16_t)lo.x; w[1] = (bf16_t)lo.y;
                w[2] = (bf16_t)lo.z; w[3] = (bf16_t)lo.w;
                w[4] = (bf16_t)hi.x; w[5] = (bf16_t)hi.y;
                w[6] = (bf16_t)hi.z; w[7] = (bf16_t)hi.w;
                a0[kk * 2 + mi] = w;
            }
    }

    // ---- 25 bodies, 2x unrolled, rotating named reg sets ----
    for (int tt = 0; tt < 24; tt += 2) {
        gemm_body(b0, b1, a0, a1, tt,     bbase, abase, acc);
        gemm_body(b1, b0, a1, a0, tt + 1, bbase, abase, acc);
    }
    gemm_body(b0, b1, a0, a1, 24, bbase, abase, acc);

    // ---- logits = 2*dot - |p|^2 ----
    #pragma unroll
    for (int mi = 0; mi < 2; ++mi)
        #pragma unroll
        for (int ni = 0; ni < 4; ++ni)
            #pragma unroll
            for (int j = 0; j < 4; ++j)
                acc[mi][ni][j] = 2.f * acc[mi][ni][j] - p2c[ni];

    // ---- fused log_softmax over 512 cols ----
    float rmax[2][4];
    #pragma unroll
    for (int mi = 0; mi < 2; ++mi)
        #pragma unroll
        for (int j = 0; j < 4; ++j) {
            float m = acc[mi][0][j];
            #pragma unroll
            for (int ni = 1; ni < 4; ++ni) m = fmaxf(m, acc[mi][ni][j]);
            rmax[mi][j] = m;
        }
    #pragma unroll
    for (int o = 1; o < 16; o <<= 1)
        #pragma unroll
        for (int mi = 0; mi < 2; ++mi)
            #pragma unroll
            for (int j = 0; j < 4; ++j)
                rmax[mi][j] = fmaxf(rmax[mi][j], __shfl_xor(rmax[mi][j], o));
    if (r == 0) {
        #pragma unroll
        for (int mi = 0; mi < 2; ++mi)
            #pragma unroll
            for (int j = 0; j < 4; ++j)
                red[(mi * 16 + g * 4 + j) * 8 + wid] = rmax[mi][j];
    }
    __syncthreads();
    if (tid < 32) {
        float m = red[tid * 8];
        #pragma unroll
        for (int w = 1; w < 8; ++w) m = fmaxf(m, red[tid * 8 + w]);
        gmaxs[tid] = m;
    }
    __syncthreads();

    float rsum[2][4];
    #pragma unroll
    for (int mi = 0; mi < 2; ++mi)
        #pragma unroll
        for (int j = 0; j < 4; ++j) {
            float gm = gmaxs[mi * 16 + g * 4 + j];
            float s = 0.f;
            #pragma unroll
            for (int ni = 0; ni < 4; ++ni) s += expf(acc[mi][ni][j] - gm);
            rsum[mi][j] = s;
        }
    #pragma unroll
    for (int o = 1; o < 16; o <<= 1)
        #pragma unroll
        for (int mi = 0; mi < 2; ++mi)
            #pragma unroll
            for (int j = 0; j < 4; ++j)
                rsum[mi][j] += __shfl_xor(rsum[mi][j], o);
    if (r == 0) {
        #pragma unroll
        for (int mi = 0; mi < 2; ++mi)
            #pragma unroll
            for (int j = 0; j < 4; ++j)
                red[(mi * 16 + g * 4 + j) * 8 + wid] = rsum[mi][j];
    }
    __syncthreads();
    if (tid < 32) {
        float s = 0.f;
        #pragma unroll
        for (int w = 0; w < 8; ++w) s += red[tid * 8 + w];
        lses[tid] = gmaxs[tid] + logf(s);
    }
    __syncthreads();

    // ---- write output ----
    #pragma unroll
    for (int mi = 0; mi < 2; ++mi) {
        #pragma unroll
        for (int j = 0; j < 4; ++j) {
            float l = lses[mi * 16 + g * 4 + j];
            size_t rowoff = (size_t)(m0 + mi * 16 + g * 4 + j) * NC;
            #pragma unroll
            for (int ni = 0; ni < 4; ++ni)
                out[rowoff + wid * 64 + ni * 16 + r] = acc[mi][ni][j] - l;
        }
    }
}

// ---------------------------------------------------------------------------
extern "C" void kernel_launch(void* const* d_in, const int* in_sizes, int n_in,
                              void* d_out, int out_size, void* d_ws, size_t ws_size,
                              hipStream_t stream)
{
    const float* sup = (const float*)d_in[0];   // [2560,64,5,5]
    const float* qry = (const float*)d_in[1];   // [8192,64,5,5]
    const int*   lab = (const int*)d_in[2];     // [2560]
    float* out = (float*)d_out;                 // [8192,512]

    char* ws = (char*)d_ws;
    bf16_t* protos = (bf16_t*)ws;               // 512*1600*2 = 1,638,400 B
    float*  p2     = (float*)(ws + 1638400);    // 2 KB

    proto_kernel<<<NC, 256, 0, stream>>>(sup, lab, protos, p2);
    fused_kernel<<<NQ / 32, 512, 0, stream>>>(qry, protos, p2, out);
}

// Round 7
// 56.166 us; speedup vs baseline: 1.9970x; 1.9970x over previous
//
#include <hip/hip_runtime.h>
#include <hip/hip_bf16.h>
#include <cstdint>
#include <cstddef>

#define NS 2560
#define NQ 8192
#define NC 512
#define DD 1600

typedef __bf16 bf16_t;
typedef __bf16 bf16x4 __attribute__((ext_vector_type(4)));
typedef __bf16 bf16x8 __attribute__((ext_vector_type(8)));
typedef float f32x4 __attribute__((ext_vector_type(4)));

// ---------------------------------------------------------------------------
// Kernel 1: class-mean prototypes (bf16) + ||p||^2 (fp32). One block per class.
// ---------------------------------------------------------------------------
__global__ __launch_bounds__(256) void proto_kernel(
    const float* __restrict__ sup, const int* __restrict__ lab,
    bf16_t* __restrict__ protos, float* __restrict__ p2)
{
    const int m   = blockIdx.x;
    const int tid = threadIdx.x;
    __shared__ int   idxs[32];
    __shared__ int   cnt;
    __shared__ float wsum[4];
    if (tid == 0) cnt = 0;
    __syncthreads();
    for (int i = tid; i < NS; i += 256) {
        if (lab[i] == m) {
            int p = atomicAdd(&cnt, 1);
            if (p < 32) idxs[p] = i;
        }
    }
    __syncthreads();
    int n = cnt < 32 ? cnt : 32;
    if (tid == 0 && n > 1) {                       // deterministic order
        for (int a = 1; a < n; ++a) {
            int key = idxs[a]; int b = a - 1;
            while (b >= 0 && idxs[b] > key) { idxs[b+1] = idxs[b]; --b; }
            idxs[b+1] = key;
        }
    }
    __syncthreads();

    float acc[7];
    #pragma unroll
    for (int u = 0; u < 7; ++u) acc[u] = 0.f;
    for (int t = 0; t < n; ++t) {
        const float* src = sup + (size_t)idxs[t] * DD;
        #pragma unroll
        for (int u = 0; u < 7; ++u) {
            int j = tid + u * 256;
            if (j < DD) acc[u] += src[j];
        }
    }
    float inv = (n > 0) ? 1.f / (float)n : 0.f;
    float psq = 0.f;
    #pragma unroll
    for (int u = 0; u < 7; ++u) {
        int j = tid + u * 256;
        if (j < DD) {
            float p = acc[u] * inv;
            bf16_t pb = (bf16_t)p;
            protos[(size_t)m * DD + j] = pb;
            float pf = (float)pb;
            psq += pf * pf;
        }
    }
    #pragma unroll
    for (int o = 32; o > 0; o >>= 1) psq += __shfl_xor(psq, o);
    int lane = tid & 63, wid = tid >> 6;
    if (lane == 0) wsum[wid] = psq;
    __syncthreads();
    if (tid == 0) p2[m] = wsum[0] + wsum[1] + wsum[2] + wsum[3];
}

// ---------------------------------------------------------------------------
// B staging: 256 cols x 64 K bf16 tile (32 KB) via global_load_lds, linear
// LDS dest + pre-swizzled global source. 2048 granules / 256 threads = 8 each.
// ---------------------------------------------------------------------------
__device__ __forceinline__ void stage_B(const bf16_t* __restrict__ pb,
                                        char* bbuf, int k0, int tid, int wid)
{
    #pragma unroll
    for (int p = 0; p < 8; ++p) {
        int idx  = p * 256 + tid;             // 16B granule index
        int row  = idx >> 3;                  // tile-local col 0..255
        int gcol = (idx & 7) ^ (row & 7);     // inverse swizzle on source
        const bf16_t* src = pb + (size_t)row * DD + k0 + gcol * 8;
        char* dst = bbuf + (size_t)(p * 256 + wid * 64) * 16;  // wave-uniform
        __builtin_amdgcn_global_load_lds(
            (const __attribute__((address_space(1))) void*)src,
            (__attribute__((address_space(3))) void*)dst, 16, 0, 0);
    }
}

// ---------------------------------------------------------------------------
// Kernel 2: GEMM -> logits. 32 query rows x 256 classes per block, 4 waves,
// grid 512 = 2 blocks/CU (sibling block hides the per-iter barrier drain).
// 2-phase LDS double-buffer (round-3 schedule, best measured). Wave w owns
// cols [w*64, w*64+64) of the block's 256-col half. BK=64, 25 iters.
// Writes logits = 2*dot - |p|^2 straight into d_out (fp32); a separate pass
// normalizes in place.
// ---------------------------------------------------------------------------
__global__ __launch_bounds__(256, 2) void gemm_kernel(
    const float* __restrict__ q, const bf16_t* __restrict__ protos,
    const float* __restrict__ p2, float* __restrict__ out)
{
    extern __shared__ char smem[];
    // Bs0 @0 (32KB), Bs1 @32768, As0 @65536 (4KB), As1 @69632

    const int tid  = threadIdx.x;
    const int lane = tid & 63;
    const int wid  = tid >> 6;        // wave = 64-col strip 0..3
    const int r    = lane & 15;
    const int g    = lane >> 4;
    const int m0   = blockIdx.x * 32;
    const int n0   = blockIdx.y * 256;

    const bf16_t* pb = protos + (size_t)n0 * DD;

    float p2c[4];
    #pragma unroll
    for (int ni = 0; ni < 4; ++ni) p2c[ni] = p2[n0 + wid * 64 + ni * 16 + r];

    f32x4 acc[2][4];
    #pragma unroll
    for (int mi = 0; mi < 2; ++mi)
        #pragma unroll
        for (int ni = 0; ni < 4; ++ni)
            acc[mi][ni] = (f32x4){0.f, 0.f, 0.f, 0.f};

    // A staging coords: granule g2 = u*256+tid; row = g2>>4, cg = g2&15
    const int ar0 = tid >> 4, ac0 = tid & 15;           // u = 0
    const int ar1 = (256 + tid) >> 4, ac1 = tid & 15;   // u = 1 (rows 16..31)
    const float* ap0 = q + (size_t)(m0 + ar0) * DD + ac0 * 4;
    const float* ap1 = q + (size_t)(m0 + ar1) * DD + ac1 * 4;
    const int ao0 = (ar0 * 128 + ac0 * 8) ^ ((ar0 & 7) << 4);
    const int ao1 = (ar1 * 128 + ac1 * 8) ^ ((ar1 & 7) << 4);

    // ---- prologue: stage tile 0 ----
    {
        float4 f0 = *(const float4*)(ap0);
        float4 f1 = *(const float4*)(ap1);
        stage_B(pb, smem, 0, tid, wid);
        bf16x4 w0, w1;
        w0[0] = (bf16_t)f0.x; w0[1] = (bf16_t)f0.y; w0[2] = (bf16_t)f0.z; w0[3] = (bf16_t)f0.w;
        w1[0] = (bf16_t)f1.x; w1[1] = (bf16_t)f1.y; w1[2] = (bf16_t)f1.z; w1[3] = (bf16_t)f1.w;
        *(bf16x4*)(smem + 65536 + ao0) = w0;
        *(bf16x4*)(smem + 65536 + ao1) = w1;
        __syncthreads();
    }

    for (int t = 0; t < 25; ++t) {
        const int cur = t & 1;
        const char* bs  = smem + cur * 32768;
        char*       bsn = smem + (cur ^ 1) * 32768;
        const char* as  = smem + 65536 + cur * 4096;
        char*       asn = smem + 65536 + (cur ^ 1) * 4096;
        const bool  pre = (t < 24);

        // ---- issue next tile: A fp32 to regs first, then B gloads ----
        float4 fA0, fA1;
        if (pre) {
            fA0 = *(const float4*)(ap0 + (t + 1) * 64);
            fA1 = *(const float4*)(ap1 + (t + 1) * 64);
            stage_B(pb, bsn, (t + 1) * 64, tid, wid);
        }

        // ---- compute current tile: 2 K-slices of 32, 16 MFMA ----
        #pragma unroll
        for (int kk = 0; kk < 2; ++kk) {
            bf16x8 af[2], bfr[4];
            #pragma unroll
            for (int mi = 0; mi < 2; ++mi) {
                int ab = ((mi * 16 + r) * 128 + kk * 64 + g * 16) ^ ((r & 7) << 4);
                af[mi] = *(const bf16x8*)(as + ab);
            }
            #pragma unroll
            for (int ni = 0; ni < 4; ++ni) {
                int c  = wid * 64 + ni * 16 + r;   // LDS row (tile-local col)
                int bb = (c * 128 + kk * 64 + g * 16) ^ ((c & 7) << 4);
                bfr[ni] = *(const bf16x8*)(bs + bb);
            }
            #pragma unroll
            for (int mi = 0; mi < 2; ++mi)
                #pragma unroll
                for (int ni = 0; ni < 4; ++ni)
                    acc[mi][ni] = __builtin_amdgcn_mfma_f32_16x16x32_bf16(
                        af[mi], bfr[ni], acc[mi][ni], 0, 0, 0);
        }

        // ---- convert + write A(t+1) into other buffer ----
        if (pre) {
            bf16x4 w0, w1;
            w0[0] = (bf16_t)fA0.x; w0[1] = (bf16_t)fA0.y;
            w0[2] = (bf16_t)fA0.z; w0[3] = (bf16_t)fA0.w;
            w1[0] = (bf16_t)fA1.x; w1[1] = (bf16_t)fA1.y;
            w1[2] = (bf16_t)fA1.z; w1[3] = (bf16_t)fA1.w;
            *(bf16x4*)(asn + ao0) = w0;
            *(bf16x4*)(asn + ao1) = w1;
        }
        __syncthreads();   // vmcnt(0)+lgkmcnt(0) drain completes next tile
    }

    // ---- write logits = 2*dot - |p|^2 ----
    #pragma unroll
    for (int mi = 0; mi < 2; ++mi) {
        #pragma unroll
        for (int j = 0; j < 4; ++j) {
            size_t rowoff = (size_t)(m0 + mi * 16 + g * 4 + j) * NC + n0;
            #pragma unroll
            for (int ni = 0; ni < 4; ++ni)
                out[rowoff + wid * 64 + ni * 16 + r] =
                    2.f * acc[mi][ni][j] - p2c[ni];
        }
    }
}

// ---------------------------------------------------------------------------
// Kernel 3: in-place row log_softmax on d_out. One wave per row.
// ---------------------------------------------------------------------------
__global__ __launch_bounds__(256) void lsm_kernel(float* __restrict__ io)
{
    const int row  = blockIdx.x * 4 + (threadIdx.x >> 6);
    const int lane = threadIdx.x & 63;
    float* p = io + (size_t)row * NC + lane * 8;

    float4 a = *(const float4*)(p);
    float4 b = *(const float4*)(p + 4);
    float v[8] = {a.x, a.y, a.z, a.w, b.x, b.y, b.z, b.w};

    float mx = v[0];
    #pragma unroll
    for (int i = 1; i < 8; ++i) mx = fmaxf(mx, v[i]);
    #pragma unroll
    for (int o = 32; o > 0; o >>= 1) mx = fmaxf(mx, __shfl_xor(mx, o));
    float se = 0.f;
    #pragma unroll
    for (int i = 0; i < 8; ++i) se += expf(v[i] - mx);
    #pragma unroll
    for (int o = 32; o > 0; o >>= 1) se += __shfl_xor(se, o);
    float lz = mx + logf(se);

    float4 o1 = {v[0]-lz, v[1]-lz, v[2]-lz, v[3]-lz};
    float4 o2 = {v[4]-lz, v[5]-lz, v[6]-lz, v[7]-lz};
    *(float4*)(p)     = o1;
    *(float4*)(p + 4) = o2;
}

// ---------------------------------------------------------------------------
extern "C" void kernel_launch(void* const* d_in, const int* in_sizes, int n_in,
                              void* d_out, int out_size, void* d_ws, size_t ws_size,
                              hipStream_t stream)
{
    const float* sup = (const float*)d_in[0];   // [2560,64,5,5]
    const float* qry = (const float*)d_in[1];   // [8192,64,5,5]
    const int*   lab = (const int*)d_in[2];     // [2560]
    float* out = (float*)d_out;                 // [8192,512]

    char* ws = (char*)d_ws;
    bf16_t* protos = (bf16_t*)ws;               // 512*1600*2 = 1,638,400 B
    float*  p2     = (float*)(ws + 1638400);    // 2 KB

    const int smem_bytes = 73728;               // 2x32KB B + 2x4KB A
    hipFuncSetAttribute(reinterpret_cast<const void*>(gemm_kernel),
                        hipFuncAttributeMaxDynamicSharedMemorySize, smem_bytes);

    proto_kernel<<<NC, 256, 0, stream>>>(sup, lab, protos, p2);
    gemm_kernel<<<dim3(NQ / 32, 2), 256, smem_bytes, stream>>>(qry, protos, p2, out);
    lsm_kernel<<<NQ / 4, 256, 0, stream>>>(out);
}